// Round 1
// baseline (500.346 us; speedup 1.0000x reference)
//
#include <hip/hip_runtime.h>

// SpatialShift: (ns=128, m=12, t=784, c=64) f32, n_segment=16 (H=W=4), shift=1.
// out[ns,m,t,c] = x[ns + (dh*4+dw), m, t, c] where (dh,dw) depends on chunk
// k = (m*64+c)/48:
//   k=0: src h+1 (OOR->0)   k=1: src h-1 (OOR->0)
//   k=2: src w+1 (OOR->0)   k=3: src w-1 (OOR->0)
//   k=4: src (h-1,w-1) OOR->identity   k=5: (h+1,w+1) OOR->identity
//   k=6: src (h-1,w+1) OOR->identity   k=7: (h+1,w-1) OOR->identity
//   k>=8: identity
// 48 % 16 == 0 so any aligned float4 group is within one chunk.

#define T_DIM 784
#define C4 16                       // float4 per (ns,m,t) row
#define SEG4 (12 * T_DIM * C4)      // float4 per segment step in ns: 150528
#define TOTAL4 (128 * SEG4)         // 19267584

// dh+1 / dw+1 packed 2 bits per k (k=0..8); k>=8 clamps to entry 8 (identity).
__device__ __forceinline__ int unpack(unsigned tbl, int k) {
    return (int)((tbl >> (2 * k)) & 3u) - 1;
}

__global__ __launch_bounds__(256) void spatial_shift_kernel(
    const float4* __restrict__ in, float4* __restrict__ out) {
    constexpr unsigned DH = (2u << 0) | (0u << 2) | (1u << 4) | (1u << 6) |
                            (0u << 8) | (2u << 10) | (0u << 12) | (2u << 14) |
                            (1u << 16);
    constexpr unsigned DW = (1u << 0) | (1u << 2) | (2u << 4) | (0u << 6) |
                            (0u << 8) | (2u << 10) | (2u << 12) | (0u << 14) |
                            (1u << 16);
    int stride = gridDim.x * blockDim.x;
    for (int g = blockIdx.x * blockDim.x + threadIdx.x; g < TOTAL4; g += stride) {
        int c4  = g & 15;             // float4 index within c (0..15)
        int row = g >> 4;             // (ns*12 + m)*784 + t
        int mt  = row / T_DIM;        // ns*12 + m   (magic-mul)
        int ns  = mt / 12;            // magic-mul
        int m   = mt - ns * 12;
        int h   = (ns >> 2) & 3;
        int w   = ns & 3;

        int ch = m * 64 + c4 * 4;
        int k  = ch / 48;             // 0..15
        if (k > 8) k = 8;
        int dh = unpack(DH, k);
        int dw = unpack(DW, k);

        int hs = h + dh, ws = w + dw;
        bool valid = ((unsigned)hs < 4u) && ((unsigned)ws < 4u);

        float4 v;
        if (valid) {
            v = in[g + (dh * 4 + dw) * SEG4];
        } else if (k >= 4) {
            v = in[g];                // diagonal/identity chunks: border keeps x
        } else {
            v = make_float4(0.f, 0.f, 0.f, 0.f);  // axis chunks: border is 0
        }
        out[g] = v;
    }
}

extern "C" void kernel_launch(void* const* d_in, const int* in_sizes, int n_in,
                              void* d_out, int out_size, void* d_ws, size_t ws_size,
                              hipStream_t stream) {
    const float4* in = (const float4*)d_in[0];
    float4* out = (float4*)d_out;
    dim3 grid(4096), block(256);
    spatial_shift_kernel<<<grid, block, 0, stream>>>(in, out);
}